// Round 6
// baseline (1147.108 us; speedup 1.0000x reference)
//
#include <hip/hip_runtime.h>
#include <hip/hip_bf16.h>

#ifndef MIN
#define MIN(a,b) ((a)<(b)?(a):(b))
#endif

#define RFL(x) __builtin_amdgcn_readfirstlane(x)

// ---------------------------------------------------------------------------
// fused_cm: per 64-row tile of card/merchant nodes:
//   agg[r][0:85] = sum_{e in adj(r)} x_trans[e][0:85]   (gathered into LDS)
//   h[r][c]  = relu( agg[r,:]@Wsum[:,c] + bsum[c] + s1[base+r]*wv1[c] )
//   out0[r][c] = h[r,:]@W2[:,c]
// h aliased into xbuf. lane=row in compute phases; wave gathers 16 rows.
// ---------------------------------------------------------------------------
__global__ __launch_bounds__(256, 7)
void fused_cm(const float* __restrict__ xt,            // x_trans [Nt][85]
              const int* __restrict__ off, const int* __restrict__ adj,
              int segbase, int M,
              const float* __restrict__ Wsum,          // [85][64]
              const float* __restrict__ bsum,          // [64]
              const float* __restrict__ s1, const float* __restrict__ wv1,
              const float* __restrict__ W2,            // [64][64]
              float* __restrict__ out0)
{
    constexpr int K = 85;
    __shared__ float xbuf[64 * K];
    const int tid  = threadIdx.x;
    const int lane = tid & 63;
    const int wid  = tid >> 6;
    const int c0   = RFL(wid * 16);

    const int ntiles = (M + 63) >> 6;
    for (int t = blockIdx.x; t < ntiles; t += gridDim.x) {
        const int base = t << 6;
        const int rows = MIN(64, M - base);
        __syncthreads();
        // ---- gather stage: wave wid owns rows wid*16..wid*16+15 ----
        for (int rr = 0; rr < 16; ++rr) {
            const int r = wid * 16 + rr;
            if (r >= rows) break;
            const int i = segbase + base + r;
            const int s = (i == 0) ? 0 : off[i - 1];
            const int e = off[i];
            float a0 = 0.f, a1 = 0.f;
            for (int j = s; j < e; ++j) {
                const float* xr = xt + (size_t)adj[j] * K;
                a0 += xr[lane];
                if (lane < 21) a1 += xr[64 + lane];
            }
            xbuf[r * K + lane] = a0;
            if (lane < 21) xbuf[r * K + 64 + lane] = a1;
        }
        __syncthreads();
        // ---- phase 1: h row in registers (lane = row) ----
        float acc[16];
#pragma unroll
        for (int j = 0; j < 16; ++j) acc[j] = bsum[c0 + j];
        {
            const float sv1 = (lane < rows) ? s1[base + lane] : 0.f;
#pragma unroll
            for (int j = 0; j < 16; ++j) acc[j] = fmaf(sv1, wv1[c0 + j], acc[j]);
        }
        {
            const float* xr = xbuf + lane * K;
#pragma unroll 5
            for (int k = 0; k < K; ++k) {
                const float xk = xr[k];
                const float* wk = Wsum + k * 64 + c0;
#pragma unroll
                for (int j = 0; j < 16; ++j) acc[j] = fmaf(xk, wk[j], acc[j]);
            }
        }
        __syncthreads();
#pragma unroll
        for (int j = 0; j < 16; ++j) xbuf[lane * K + c0 + j] = fmaxf(acc[j], 0.f);
        __syncthreads();
        // ---- phase 2 ----
        float a2[16];
#pragma unroll
        for (int j = 0; j < 16; ++j) a2[j] = 0.f;
        {
            const float* hr = xbuf + lane * K;
#pragma unroll 4
            for (int k = 0; k < 64; ++k) {
                const float hk = hr[k];
                const float* wk = W2 + k * 64 + c0;
#pragma unroll
                for (int j = 0; j < 16; ++j) a2[j] = fmaf(hk, wk[j], a2[j]);
            }
        }
        if (lane < rows) {
            float* o0 = out0 + (size_t)(base + lane) * 64 + c0;
#pragma unroll
            for (int j4 = 0; j4 < 4; ++j4)
                reinterpret_cast<float4*>(o0)[j4] =
                    make_float4(a2[4*j4], a2[4*j4+1], a2[4*j4+2], a2[4*j4+3]);
        }
    }
}

// ---------------------------------------------------------------------------
// mega_tf: per 64-row tile of transactions:
//   svc[r] = sum x_card[adjP(r)], svm[r] = sum x_merch[adjR(r)]  (LDS sbuf)
//   h[r][c]  = relu( x[r,:]@Wsum[:,c] + bsum[c] + svc[r]*wv1[c] + svm[r]*wv2[c] )
//   vR[r][c] = h[r,:]@W2[R][:,c] + b2v[R][c] + sum_{e in adjR(r)} zR[e][c]
//   out[r][o] = bl[o] + sum_c relu(v0)*wl[c][o] + relu(v1)*wl[64+c][o]
// ---------------------------------------------------------------------------
__global__ __launch_bounds__(256, 7)
void mega_tf(const float* __restrict__ in, int M,
             const float* __restrict__ Wsum,   // [85][64]
             const float* __restrict__ bsum,   // [64]
             const float* __restrict__ xc, const float* __restrict__ wv1,
             const float* __restrict__ xm, const float* __restrict__ wv2,
             const float* __restrict__ W2,     // [2][64][64] (w2_r)
             const float* __restrict__ b2v,    // [2][64]
             const float* __restrict__ z1, const float* __restrict__ z2,
             const int* __restrict__ off, const int* __restrict__ adj,
             int zb0, int zb1,                 // segment bases: Nc+Nm, Nc+Nm+Nt
             const float* __restrict__ wl, const float* __restrict__ bl,
             float* __restrict__ out)
{
    constexpr int K = 85;
    __shared__ float xbuf[64 * K];
    __shared__ float obuf[64][2];
    __shared__ float sbuf[64][2];
    const int tid  = threadIdx.x;
    const int lane = tid & 63;
    const int wid  = tid >> 6;
    const int c0   = RFL(wid * 16);

    const int ntiles = (M + 63) >> 6;
    for (int t = blockIdx.x; t < ntiles; t += gridDim.x) {
        const int base = t << 6;
        const int rows = MIN(64, M - base);
        __syncthreads();
        // ---- stage x tile ----
        {
            const int nw = rows * K;
            const float4* s4 = reinterpret_cast<const float4*>(in + (size_t)base * K);
            const int nv = nw >> 2;
            for (int i = tid; i < nv; i += 256)
                reinterpret_cast<float4*>(xbuf)[i] = s4[i];
            for (int i = (nv << 2) + tid; i < nw; i += 256)
                xbuf[i] = in[(size_t)base * K + i];
        }
        // ---- scalar gathers: threads 0-63 pays, 64-127 recv; 128+ zero obuf
        if (tid < 128) {
            const int  tt  = tid & 63;
            const bool rel = tid >= 64;
            if (tt < rows) {
                const int i = (rel ? zb1 : zb0) + base + tt;
                const int s = off[i - 1], e = off[i];
                const float* xs = rel ? xm : xc;
                float a = 0.f;
                for (int j = s; j < e; ++j) a += xs[adj[j]];
                sbuf[tt][rel] = a;
            }
        } else if (tid < 256) {
            if (tid - 128 < 128) ((float*)obuf)[tid - 128] = 0.f;
        }
        __syncthreads();
        // ---- phase 1 ----
        float acc[16];
#pragma unroll
        for (int j = 0; j < 16; ++j) acc[j] = bsum[c0 + j];
        {
            const float sv1 = sbuf[lane][0];
#pragma unroll
            for (int j = 0; j < 16; ++j) acc[j] = fmaf(sv1, wv1[c0 + j], acc[j]);
        }
        {
            const float sv2 = sbuf[lane][1];
#pragma unroll
            for (int j = 0; j < 16; ++j) acc[j] = fmaf(sv2, wv2[c0 + j], acc[j]);
        }
        {
            const float* xr = xbuf + lane * K;
#pragma unroll 5
            for (int k = 0; k < K; ++k) {
                const float xk = xr[k];
                const float* wk = Wsum + k * 64 + c0;
#pragma unroll
                for (int j = 0; j < 16; ++j) acc[j] = fmaf(xk, wk[j], acc[j]);
            }
        }
        __syncthreads();          // all phase-1 xbuf reads done
#pragma unroll
        for (int j = 0; j < 16; ++j) xbuf[lane * K + c0 + j] = fmaxf(acc[j], 0.f);
        __syncthreads();
        // ---- phase 2: v0, v1 ----
        float a0[16], a1[16];
#pragma unroll
        for (int j = 0; j < 16; ++j) {
            a0[j] = b2v[c0 + j];
            a1[j] = b2v[64 + c0 + j];
        }
        {
            const float* hr = xbuf + lane * K;
#pragma unroll 4
            for (int k = 0; k < 64; ++k) {
                const float hk = hr[k];
                const float* wk0 = W2 + k * 64 + c0;
                const float* wk1 = W2 + 4096 + k * 64 + c0;
#pragma unroll
                for (int j = 0; j < 16; ++j) {
                    a0[j] = fmaf(hk, wk0[j], a0[j]);
                    a1[j] = fmaf(hk, wk1[j], a1[j]);
                }
            }
        }
        // ---- z gathers (per-lane edge lists, avg degree ~1) ----
        if (lane < rows) {
            {
                const int i0 = zb0 + base + lane;
                const int e0 = off[i0 - 1], e1 = off[i0];
                for (int j = e0; j < e1; ++j) {
                    const float4* zr = reinterpret_cast<const float4*>(
                        z1 + (size_t)adj[j] * 64 + c0);
#pragma unroll
                    for (int q = 0; q < 4; ++q) {
                        const float4 v = zr[q];
                        a0[4*q+0] += v.x; a0[4*q+1] += v.y;
                        a0[4*q+2] += v.z; a0[4*q+3] += v.w;
                    }
                }
            }
            {
                const int i1 = zb1 + base + lane;
                const int e0 = off[i1 - 1], e1 = off[i1];
                for (int j = e0; j < e1; ++j) {
                    const float4* zr = reinterpret_cast<const float4*>(
                        z2 + (size_t)adj[j] * 64 + c0);
#pragma unroll
                    for (int q = 0; q < 4; ++q) {
                        const float4 v = zr[q];
                        a1[4*q+0] += v.x; a1[4*q+1] += v.y;
                        a1[4*q+2] += v.z; a1[4*q+3] += v.w;
                    }
                }
            }
        }
        // ---- relu + partial projection for this wave's 16 columns ----
        float pa = 0.f, pb = 0.f;
#pragma unroll
        for (int j = 0; j < 16; ++j) {
            const int c = c0 + j;
            const float v0 = fmaxf(a0[j], 0.f);
            const float v1 = fmaxf(a1[j], 0.f);
            pa += v0 * wl[c * 2 + 0] + v1 * wl[(64 + c) * 2 + 0];
            pb += v0 * wl[c * 2 + 1] + v1 * wl[(64 + c) * 2 + 1];
        }
        atomicAdd(&obuf[lane][0], pa);
        atomicAdd(&obuf[lane][1], pb);
        __syncthreads();
        if (tid < 2 * rows) {
            const int r = tid >> 1, o = tid & 1;
            out[(size_t)(base + r) * 2 + o] = obuf[r][o] + bl[o];
        }
    }
}

// ---------------------------------------------------------------------------
__global__ __launch_bounds__(256)
void prep(const float* __restrict__ w1dt, const float* __restrict__ b1t,
          float* __restrict__ wsum, float* __restrict__ bsum)
{
    const int i = blockIdx.x * 256 + threadIdx.x;
    if (i < 85 * 64) wsum[i] = w1dt[i] + w1dt[85 * 64 + i];
    if (i < 64)      bsum[i] = b1t[i] + b1t[64 + i];
}

// ---------------------------------------------------------------------------
// CSR build over ONE concatenated key space:
//   [0,Nc): card (pays src)              payload dst_pays
//   [Nc,Nc+Nm): merchant (recv src)      payload dst_recv
//   [Nc+Nm,+Nt): transaction (pays dst)  payload src_pays
//   [Nc+Nm+Nt,+Nt): transaction (recv)   payload src_recv
// ---------------------------------------------------------------------------
__global__ __launch_bounds__(256)
void hist(const int* __restrict__ sp, const int* __restrict__ dp,
          const int* __restrict__ sr, const int* __restrict__ dr,
          int E, int Nc, int Nm, int Nt, int* __restrict__ cnt)
{
    const int stride = gridDim.x * 256;
    for (int e = blockIdx.x * 256 + threadIdx.x; e < E; e += stride) {
        atomicAdd(&cnt[sp[e]], 1);
        atomicAdd(&cnt[Nc + sr[e]], 1);
        atomicAdd(&cnt[Nc + Nm + dp[e]], 1);
        atomicAdd(&cnt[Nc + Nm + Nt + dr[e]], 1);
    }
}

__global__ __launch_bounds__(256)
void scan_p1(const int* __restrict__ cnt, int n, int* __restrict__ part)
{
    __shared__ int sdata[256];
    const int b = blockIdx.x, t = threadIdx.x;
    const int base = b * 4096;
    int s = 0;
    for (int i = t; i < 4096; i += 256) {
        const int idx = base + i;
        s += (idx < n) ? cnt[idx] : 0;
    }
    sdata[t] = s; __syncthreads();
    for (int off = 128; off > 0; off >>= 1) {
        if (t < off) sdata[t] += sdata[t + off];
        __syncthreads();
    }
    if (t == 0) part[b] = sdata[0];
}

__global__ __launch_bounds__(256)
void scan_p2(int* __restrict__ part, int nb)
{
    __shared__ int sdata[256];
    const int t = threadIdx.x;
    int carry = 0;
    for (int base = 0; base < nb; base += 256) {
        const int idx = base + t;
        const int v = (idx < nb) ? part[idx] : 0;
        sdata[t] = v; __syncthreads();
        for (int off = 1; off < 256; off <<= 1) {
            const int x = (t >= off) ? sdata[t - off] : 0;
            __syncthreads();
            sdata[t] += x;
            __syncthreads();
        }
        const int incl  = sdata[t];
        const int total = sdata[255];
        if (idx < nb) part[idx] = carry + incl - v;
        carry += total;
        __syncthreads();
    }
}

__global__ __launch_bounds__(256)
void scan_p3(int* __restrict__ cnt, int n, const int* __restrict__ part)
{
    __shared__ int sums[256];
    const int b = blockIdx.x, t = threadIdx.x;
    const int base = b * 4096 + t * 16;
    int v[16];
    int s = 0;
#pragma unroll
    for (int j = 0; j < 16; ++j) {
        const int idx = base + j;
        v[j] = (idx < n) ? cnt[idx] : 0;
        s += v[j];
    }
    sums[t] = s; __syncthreads();
    for (int off = 1; off < 256; off <<= 1) {
        const int x = (t >= off) ? sums[t - off] : 0;
        __syncthreads();
        sums[t] += x;
        __syncthreads();
    }
    int run = part[b] + sums[t] - s;
#pragma unroll
    for (int j = 0; j < 16; ++j) {
        const int idx = base + j;
        if (idx < n) cnt[idx] = run;
        run += v[j];
    }
}

__global__ __launch_bounds__(256)
void fill(const int* __restrict__ sp, const int* __restrict__ dp,
          const int* __restrict__ sr, const int* __restrict__ dr,
          int E, int Nc, int Nm, int Nt,
          int* __restrict__ off, int* __restrict__ adj)
{
    const int stride = gridDim.x * 256;
    for (int e = blockIdx.x * 256 + threadIdx.x; e < E; e += stride) {
        int p;
        p = atomicAdd(&off[sp[e]], 1);                adj[p] = dp[e];
        p = atomicAdd(&off[Nc + sr[e]], 1);           adj[p] = dr[e];
        p = atomicAdd(&off[Nc + Nm + dp[e]], 1);      adj[p] = sp[e];
        p = atomicAdd(&off[Nc + Nm + Nt + dr[e]], 1); adj[p] = sr[e];
    }
}

// ---------------------------------------------------------------------------
extern "C" void kernel_launch(void* const* d_in, const int* in_sizes, int n_in,
                              void* d_out, int out_size, void* d_ws, size_t ws_size,
                              hipStream_t stream)
{
    const float* x_card   = (const float*)d_in[0];
    const float* x_merch  = (const float*)d_in[1];
    const float* x_trans  = (const float*)d_in[2];
    const float* w1_src_t = (const float*)d_in[3];   // [2,1,64]
    const float* w1_dst_t = (const float*)d_in[4];   // [2,85,64]
    const float* b1_t     = (const float*)d_in[5];   // [2,64]
    const float* w1_src_r = (const float*)d_in[6];   // [2,85,64]
    const float* w1_dst_r = (const float*)d_in[7];   // [2,1,64]
    const float* b1_r     = (const float*)d_in[8];   // [2,64]
    const float* w2_l     = (const float*)d_in[9];   // [4,64,64]
    const float* w2_r     = (const float*)d_in[10];  // [4,64,64]
    const float* b2       = (const float*)d_in[11];  // [4,64]
    const float* w_lin    = (const float*)d_in[12];  // [128,2]
    const float* b_lin    = (const float*)d_in[13];  // [2]
    const int*   src_pays = (const int*)d_in[14];
    const int*   dst_pays = (const int*)d_in[15];
    const int*   src_recv = (const int*)d_in[16];
    const int*   dst_recv = (const int*)d_in[17];
    float*       out      = (float*)d_out;

    const int Nc = in_sizes[0];
    const int Nm = in_sizes[1];
    const int Nt = in_sizes[2] / 85;
    const int E  = in_sizes[14];
    const int Ntot = Nc + Nm + 2 * Nt;
    const int NB   = (Ntot + 4095) / 4096;

    // workspace layout
    char* wsp = (char*)d_ws;
    auto alloc = [&](size_t bytes) -> void* {
        char* p = wsp;
        wsp += (bytes + 255) & ~(size_t)255;
        return (void*)p;
    };
    int*   cnt  = (int*)alloc((size_t)Ntot * 4);     // -> off after scan/fill
    const size_t zero_bytes = (size_t)(wsp - (char*)d_ws);
    int*   part = (int*)alloc((size_t)(NB + 1) * 4);
    int*   adj  = (int*)alloc((size_t)4 * E * 4);
    float* wsum = (float*)alloc((size_t)85 * 64 * 4);
    float* bsum = (float*)alloc((size_t)64 * 4);
    float* z1   = (float*)alloc((size_t)Nc * 64 * 4);
    float* z2   = (float*)alloc((size_t)Nm * 64 * 4);
    (void)ws_size; (void)n_in; (void)out_size;

    hipMemsetAsync(d_ws, 0, zero_bytes, stream);   // zero cnt only

    const dim3 blk(256);
    const int gE = MIN((E + 255) / 256, 2048);
    auto tiles = [](int M) { return (M + 63) / 64; };

    // weight precompute
    prep<<<(85 * 64 + 255) / 256, blk, 0, stream>>>(w1_dst_t, b1_t, wsum, bsum);

    // ---- CSR build ----
    hist<<<gE, blk, 0, stream>>>(src_pays, dst_pays, src_recv, dst_recv, E, Nc, Nm, Nt, cnt);
    scan_p1<<<NB, blk, 0, stream>>>(cnt, Ntot, part);
    scan_p2<<<1, blk, 0, stream>>>(part, NB);
    scan_p3<<<NB, blk, 0, stream>>>(cnt, Ntot, part);
    fill<<<gE, blk, 0, stream>>>(src_pays, dst_pays, src_recv, dst_recv, E, Nc, Nm, Nt, cnt, adj);

    // ---- card/merchant pipelines: gather -> h -> z (fused) ----
    fused_cm<<<tiles(Nc), blk, 0, stream>>>(
        x_trans, cnt, adj, 0, Nc,
        w1_src_r, b1_r, x_card, w1_dst_r, w2_l, z1);
    fused_cm<<<tiles(Nm), blk, 0, stream>>>(
        x_trans, cnt, adj, Nc, Nm,
        w1_src_r + 85 * 64, b1_r + 64, x_merch, w1_dst_r + 64,
        w2_l + 64 * 64, z2);

    // ---- megakernel: x_trans -> h_t -> v0,v1 (+scalar & z gathers) -> out ----
    mega_tf<<<tiles(Nt), blk, 0, stream>>>(
        x_trans, Nt, wsum, bsum,
        x_card, w1_src_t, x_merch, w1_src_t + 64,
        w2_r, b2, z1, z2,
        cnt, adj, Nc + Nm, Nc + Nm + Nt,
        w_lin, b_lin, out);
}

// Round 7
// 727.372 us; speedup vs baseline: 1.5771x; 1.5771x over previous
//
#include <hip/hip_runtime.h>
#include <hip/hip_bf16.h>

#ifndef MIN
#define MIN(a,b) ((a)<(b)?(a):(b))
#endif

#define RFL(x) __builtin_amdgcn_readfirstlane(x)

// ---------------------------------------------------------------------------
// gather85: per card/merchant node, sum x_trans rows of its edge list.
// Wave per node (grid sized so every node gets its own wave -> max MLP);
// lane = channel; edge loop unrolled x2 for memory-level parallelism.
// ---------------------------------------------------------------------------
__global__ __launch_bounds__(256)
void gather85(const float* __restrict__ xt,
              const int* __restrict__ off, const int* __restrict__ adj,
              int Nc, int Nm,
              float* __restrict__ aggC, float* __restrict__ aggM)
{
    const int lane = threadIdx.x & 63;
    const int gw   = blockIdx.x * (blockDim.x >> 6) + (threadIdx.x >> 6);
    const int nw   = gridDim.x * (blockDim.x >> 6);
    const int N = Nc + Nm;
    for (int i = gw; i < N; i += nw) {
        const int s = (i == 0) ? 0 : off[i - 1];
        const int e = off[i];
        float a0 = 0.f, a1 = 0.f, b0 = 0.f, b1 = 0.f;
        int j = s;
        for (; j + 1 < e; j += 2) {
            const float* xr0 = xt + (size_t)adj[j] * 85;
            const float* xr1 = xt + (size_t)adj[j + 1] * 85;
            a0 += xr0[lane];
            b0 += xr1[lane];
            if (lane < 21) {
                a1 += xr0[64 + lane];
                b1 += xr1[64 + lane];
            }
        }
        if (j < e) {
            const float* xr = xt + (size_t)adj[j] * 85;
            a0 += xr[lane];
            if (lane < 21) a1 += xr[64 + lane];
        }
        a0 += b0; a1 += b1;
        float* dst = (i < Nc) ? aggC + (size_t)i * 85 : aggM + (size_t)(i - Nc) * 85;
        dst[lane] = a0;
        if (lane < 21) dst[64 + lane] = a1;
    }
}

// ---------------------------------------------------------------------------
// fused_small: per 64-row tile of `in` [M][85]:
//   h[r][c] = relu( in[r,:]@Wsum[:,c] + bsum[c] + s1[r]*wv1[c] )
//   out0[r][c] = h[r,:]@W2[:,c]
// h aliased into xbuf (pitch 85) -> 22KB LDS, 7 blocks/CU.
// ---------------------------------------------------------------------------
__global__ __launch_bounds__(256, 7)
void fused_small(const float* __restrict__ in, int M,
                 const float* __restrict__ Wsum,   // [85][64]
                 const float* __restrict__ bsum,   // [64]
                 const float* __restrict__ s1, const float* __restrict__ wv1,
                 const float* __restrict__ W2,     // [64][64]
                 float* __restrict__ out0)
{
    constexpr int K = 85;
    __shared__ float xbuf[64 * K];
    const int tid  = threadIdx.x;
    const int lane = tid & 63;
    const int wid  = tid >> 6;
    const int c0   = RFL(wid * 16);

    const int ntiles = (M + 63) >> 6;
    for (int t = blockIdx.x; t < ntiles; t += gridDim.x) {
        const int base = t << 6;
        const int rows = MIN(64, M - base);
        __syncthreads();
        {
            const int nw = rows * K;
            const float4* s4 = reinterpret_cast<const float4*>(in + (size_t)base * K);
            const int nv = nw >> 2;
            for (int i = tid; i < nv; i += 256)
                reinterpret_cast<float4*>(xbuf)[i] = s4[i];
            for (int i = (nv << 2) + tid; i < nw; i += 256)
                xbuf[i] = in[(size_t)base * K + i];
        }
        __syncthreads();
        // phase 1
        float acc[16];
#pragma unroll
        for (int j = 0; j < 16; ++j) acc[j] = bsum[c0 + j];
        {
            const float sv1 = (lane < rows) ? s1[base + lane] : 0.f;
#pragma unroll
            for (int j = 0; j < 16; ++j) acc[j] = fmaf(sv1, wv1[c0 + j], acc[j]);
        }
        {
            const float* xr = xbuf + lane * K;
#pragma unroll 5
            for (int k = 0; k < K; ++k) {
                const float xk = xr[k];
                const float* wk = Wsum + k * 64 + c0;
#pragma unroll
                for (int j = 0; j < 16; ++j) acc[j] = fmaf(xk, wk[j], acc[j]);
            }
        }
        __syncthreads();          // all phase-1 xbuf reads done
#pragma unroll
        for (int j = 0; j < 16; ++j) xbuf[lane * K + c0 + j] = fmaxf(acc[j], 0.f);
        __syncthreads();
        // phase 2
        float a2[16];
#pragma unroll
        for (int j = 0; j < 16; ++j) a2[j] = 0.f;
        {
            const float* hr = xbuf + lane * K;
#pragma unroll 4
            for (int k = 0; k < 64; ++k) {
                const float hk = hr[k];
                const float* wk = W2 + k * 64 + c0;
#pragma unroll
                for (int j = 0; j < 16; ++j) a2[j] = fmaf(hk, wk[j], a2[j]);
            }
        }
        if (lane < rows) {
            float* o0 = out0 + (size_t)(base + lane) * 64 + c0;
#pragma unroll
            for (int j4 = 0; j4 < 4; ++j4)
                reinterpret_cast<float4*>(o0)[j4] =
                    make_float4(a2[4*j4], a2[4*j4+1], a2[4*j4+2], a2[4*j4+3]);
        }
    }
}

// ---------------------------------------------------------------------------
// mega_tf: per 64-row tile of transactions:
//   svc[r] = sum x_card[adjP(r)], svm[r] = sum x_merch[adjR(r)]  (LDS sbuf)
//   h[r][c]  = relu( x[r,:]@Wsum[:,c] + bsum[c] + svc[r]*wv1[c] + svm[r]*wv2[c] )
//   vR[r][c] = h[r,:]@W2[R][:,c] + b2v[R][c] + sum_{e in adjR(r)} zR[e][c]
//   out[r][o] = bl[o] + sum_c relu(v0)*wl[c][o] + relu(v1)*wl[64+c][o]
// ---------------------------------------------------------------------------
__global__ __launch_bounds__(256, 7)
void mega_tf(const float* __restrict__ in, int M,
             const float* __restrict__ Wsum,   // [85][64]
             const float* __restrict__ bsum,   // [64]
             const float* __restrict__ xc, const float* __restrict__ wv1,
             const float* __restrict__ xm, const float* __restrict__ wv2,
             const float* __restrict__ W2,     // [2][64][64] (w2_r)
             const float* __restrict__ b2v,    // [2][64]
             const float* __restrict__ z1, const float* __restrict__ z2,
             const int* __restrict__ off, const int* __restrict__ adj,
             int zb0, int zb1,                 // segment bases: Nc+Nm, Nc+Nm+Nt
             const float* __restrict__ wl, const float* __restrict__ bl,
             float* __restrict__ out)
{
    constexpr int K = 85;
    __shared__ float xbuf[64 * K];
    __shared__ float obuf[64][2];
    __shared__ float sbuf[64][2];
    const int tid  = threadIdx.x;
    const int lane = tid & 63;
    const int wid  = tid >> 6;
    const int c0   = RFL(wid * 16);

    const int ntiles = (M + 63) >> 6;
    for (int t = blockIdx.x; t < ntiles; t += gridDim.x) {
        const int base = t << 6;
        const int rows = MIN(64, M - base);
        __syncthreads();
        // ---- stage x tile ----
        {
            const int nw = rows * K;
            const float4* s4 = reinterpret_cast<const float4*>(in + (size_t)base * K);
            const int nv = nw >> 2;
            for (int i = tid; i < nv; i += 256)
                reinterpret_cast<float4*>(xbuf)[i] = s4[i];
            for (int i = (nv << 2) + tid; i < nw; i += 256)
                xbuf[i] = in[(size_t)base * K + i];
        }
        // ---- scalar gathers: threads 0-63 pays, 64-127 recv; 128+ zero obuf
        if (tid < 128) {
            const int  tt  = tid & 63;
            const bool rel = tid >= 64;
            if (tt < rows) {
                const int i = (rel ? zb1 : zb0) + base + tt;
                const int s = off[i - 1], e = off[i];
                const float* xs = rel ? xm : xc;
                float a = 0.f;
                for (int j = s; j < e; ++j) a += xs[adj[j]];
                sbuf[tt][rel] = a;
            }
        } else if (tid < 256) {
            if (tid - 128 < 128) ((float*)obuf)[tid - 128] = 0.f;
        }
        __syncthreads();
        // ---- phase 1 ----
        float acc[16];
#pragma unroll
        for (int j = 0; j < 16; ++j) acc[j] = bsum[c0 + j];
        {
            const float sv1 = sbuf[lane][0];
#pragma unroll
            for (int j = 0; j < 16; ++j) acc[j] = fmaf(sv1, wv1[c0 + j], acc[j]);
        }
        {
            const float sv2 = sbuf[lane][1];
#pragma unroll
            for (int j = 0; j < 16; ++j) acc[j] = fmaf(sv2, wv2[c0 + j], acc[j]);
        }
        {
            const float* xr = xbuf + lane * K;
#pragma unroll 5
            for (int k = 0; k < K; ++k) {
                const float xk = xr[k];
                const float* wk = Wsum + k * 64 + c0;
#pragma unroll
                for (int j = 0; j < 16; ++j) acc[j] = fmaf(xk, wk[j], acc[j]);
            }
        }
        __syncthreads();          // all phase-1 xbuf reads done
#pragma unroll
        for (int j = 0; j < 16; ++j) xbuf[lane * K + c0 + j] = fmaxf(acc[j], 0.f);
        __syncthreads();
        // ---- phase 2: v0, v1 ----
        float a0[16], a1[16];
#pragma unroll
        for (int j = 0; j < 16; ++j) {
            a0[j] = b2v[c0 + j];
            a1[j] = b2v[64 + c0 + j];
        }
        {
            const float* hr = xbuf + lane * K;
#pragma unroll 4
            for (int k = 0; k < 64; ++k) {
                const float hk = hr[k];
                const float* wk0 = W2 + k * 64 + c0;
                const float* wk1 = W2 + 4096 + k * 64 + c0;
#pragma unroll
                for (int j = 0; j < 16; ++j) {
                    a0[j] = fmaf(hk, wk0[j], a0[j]);
                    a1[j] = fmaf(hk, wk1[j], a1[j]);
                }
            }
        }
        // ---- z gathers (per-lane edge lists, avg degree ~1) ----
        if (lane < rows) {
            {
                const int i0 = zb0 + base + lane;
                const int e0 = off[i0 - 1], e1 = off[i0];
                for (int j = e0; j < e1; ++j) {
                    const float4* zr = reinterpret_cast<const float4*>(
                        z1 + (size_t)adj[j] * 64 + c0);
#pragma unroll
                    for (int q = 0; q < 4; ++q) {
                        const float4 v = zr[q];
                        a0[4*q+0] += v.x; a0[4*q+1] += v.y;
                        a0[4*q+2] += v.z; a0[4*q+3] += v.w;
                    }
                }
            }
            {
                const int i1 = zb1 + base + lane;
                const int e0 = off[i1 - 1], e1 = off[i1];
                for (int j = e0; j < e1; ++j) {
                    const float4* zr = reinterpret_cast<const float4*>(
                        z2 + (size_t)adj[j] * 64 + c0);
#pragma unroll
                    for (int q = 0; q < 4; ++q) {
                        const float4 v = zr[q];
                        a1[4*q+0] += v.x; a1[4*q+1] += v.y;
                        a1[4*q+2] += v.z; a1[4*q+3] += v.w;
                    }
                }
            }
        }
        // ---- relu + partial projection for this wave's 16 columns ----
        float pa = 0.f, pb = 0.f;
#pragma unroll
        for (int j = 0; j < 16; ++j) {
            const int c = c0 + j;
            const float v0 = fmaxf(a0[j], 0.f);
            const float v1 = fmaxf(a1[j], 0.f);
            pa += v0 * wl[c * 2 + 0] + v1 * wl[(64 + c) * 2 + 0];
            pb += v0 * wl[c * 2 + 1] + v1 * wl[(64 + c) * 2 + 1];
        }
        atomicAdd(&obuf[lane][0], pa);
        atomicAdd(&obuf[lane][1], pb);
        __syncthreads();
        if (tid < 2 * rows) {
            const int r = tid >> 1, o = tid & 1;
            out[(size_t)(base + r) * 2 + o] = obuf[r][o] + bl[o];
        }
    }
}

// ---------------------------------------------------------------------------
__global__ __launch_bounds__(256)
void prep(const float* __restrict__ w1dt, const float* __restrict__ b1t,
          float* __restrict__ wsum, float* __restrict__ bsum)
{
    const int i = blockIdx.x * 256 + threadIdx.x;
    if (i < 85 * 64) wsum[i] = w1dt[i] + w1dt[85 * 64 + i];
    if (i < 64)      bsum[i] = b1t[i] + b1t[64 + i];
}

// ---------------------------------------------------------------------------
// CSR build over ONE concatenated key space:
//   [0,Nc): card (pays src)              payload dst_pays
//   [Nc,Nc+Nm): merchant (recv src)      payload dst_recv
//   [Nc+Nm,+Nt): transaction (pays dst)  payload src_pays
//   [Nc+Nm+Nt,+Nt): transaction (recv)   payload src_recv
// ---------------------------------------------------------------------------
__global__ __launch_bounds__(256)
void hist(const int* __restrict__ sp, const int* __restrict__ dp,
          const int* __restrict__ sr, const int* __restrict__ dr,
          int E, int Nc, int Nm, int Nt, int* __restrict__ cnt)
{
    const int stride = gridDim.x * 256;
    for (int e = blockIdx.x * 256 + threadIdx.x; e < E; e += stride) {
        atomicAdd(&cnt[sp[e]], 1);
        atomicAdd(&cnt[Nc + sr[e]], 1);
        atomicAdd(&cnt[Nc + Nm + dp[e]], 1);
        atomicAdd(&cnt[Nc + Nm + Nt + dr[e]], 1);
    }
}

__global__ __launch_bounds__(256)
void scan_p1(const int* __restrict__ cnt, int n, int* __restrict__ part)
{
    __shared__ int sdata[256];
    const int b = blockIdx.x, t = threadIdx.x;
    const int base = b * 4096;
    int s = 0;
    for (int i = t; i < 4096; i += 256) {
        const int idx = base + i;
        s += (idx < n) ? cnt[idx] : 0;
    }
    sdata[t] = s; __syncthreads();
    for (int off = 128; off > 0; off >>= 1) {
        if (t < off) sdata[t] += sdata[t + off];
        __syncthreads();
    }
    if (t == 0) part[b] = sdata[0];
}

__global__ __launch_bounds__(256)
void scan_p2(int* __restrict__ part, int nb)
{
    __shared__ int sdata[256];
    const int t = threadIdx.x;
    int carry = 0;
    for (int base = 0; base < nb; base += 256) {
        const int idx = base + t;
        const int v = (idx < nb) ? part[idx] : 0;
        sdata[t] = v; __syncthreads();
        for (int off = 1; off < 256; off <<= 1) {
            const int x = (t >= off) ? sdata[t - off] : 0;
            __syncthreads();
            sdata[t] += x;
            __syncthreads();
        }
        const int incl  = sdata[t];
        const int total = sdata[255];
        if (idx < nb) part[idx] = carry + incl - v;
        carry += total;
        __syncthreads();
    }
}

__global__ __launch_bounds__(256)
void scan_p3(int* __restrict__ cnt, int n, const int* __restrict__ part)
{
    __shared__ int sums[256];
    const int b = blockIdx.x, t = threadIdx.x;
    const int base = b * 4096 + t * 16;
    int v[16];
    int s = 0;
#pragma unroll
    for (int j = 0; j < 16; ++j) {
        const int idx = base + j;
        v[j] = (idx < n) ? cnt[idx] : 0;
        s += v[j];
    }
    sums[t] = s; __syncthreads();
    for (int off = 1; off < 256; off <<= 1) {
        const int x = (t >= off) ? sums[t - off] : 0;
        __syncthreads();
        sums[t] += x;
        __syncthreads();
    }
    int run = part[b] + sums[t] - s;
#pragma unroll
    for (int j = 0; j < 16; ++j) {
        const int idx = base + j;
        if (idx < n) cnt[idx] = run;
        run += v[j];
    }
}

__global__ __launch_bounds__(256)
void fill(const int* __restrict__ sp, const int* __restrict__ dp,
          const int* __restrict__ sr, const int* __restrict__ dr,
          int E, int Nc, int Nm, int Nt,
          int* __restrict__ off, int* __restrict__ adj)
{
    const int stride = gridDim.x * 256;
    for (int e = blockIdx.x * 256 + threadIdx.x; e < E; e += stride) {
        int p;
        p = atomicAdd(&off[sp[e]], 1);                adj[p] = dp[e];
        p = atomicAdd(&off[Nc + sr[e]], 1);           adj[p] = dr[e];
        p = atomicAdd(&off[Nc + Nm + dp[e]], 1);      adj[p] = sp[e];
        p = atomicAdd(&off[Nc + Nm + Nt + dr[e]], 1); adj[p] = sr[e];
    }
}

// ---------------------------------------------------------------------------
extern "C" void kernel_launch(void* const* d_in, const int* in_sizes, int n_in,
                              void* d_out, int out_size, void* d_ws, size_t ws_size,
                              hipStream_t stream)
{
    const float* x_card   = (const float*)d_in[0];
    const float* x_merch  = (const float*)d_in[1];
    const float* x_trans  = (const float*)d_in[2];
    const float* w1_src_t = (const float*)d_in[3];   // [2,1,64]
    const float* w1_dst_t = (const float*)d_in[4];   // [2,85,64]
    const float* b1_t     = (const float*)d_in[5];   // [2,64]
    const float* w1_src_r = (const float*)d_in[6];   // [2,85,64]
    const float* w1_dst_r = (const float*)d_in[7];   // [2,1,64]
    const float* b1_r     = (const float*)d_in[8];   // [2,64]
    const float* w2_l     = (const float*)d_in[9];   // [4,64,64]
    const float* w2_r     = (const float*)d_in[10];  // [4,64,64]
    const float* b2       = (const float*)d_in[11];  // [4,64]
    const float* w_lin    = (const float*)d_in[12];  // [128,2]
    const float* b_lin    = (const float*)d_in[13];  // [2]
    const int*   src_pays = (const int*)d_in[14];
    const int*   dst_pays = (const int*)d_in[15];
    const int*   src_recv = (const int*)d_in[16];
    const int*   dst_recv = (const int*)d_in[17];
    float*       out      = (float*)d_out;

    const int Nc = in_sizes[0];
    const int Nm = in_sizes[1];
    const int Nt = in_sizes[2] / 85;
    const int E  = in_sizes[14];
    const int Ntot = Nc + Nm + 2 * Nt;
    const int NB   = (Ntot + 4095) / 4096;

    // workspace layout
    char* wsp = (char*)d_ws;
    auto alloc = [&](size_t bytes) -> void* {
        char* p = wsp;
        wsp += (bytes + 255) & ~(size_t)255;
        return (void*)p;
    };
    int*   cnt    = (int*)alloc((size_t)Ntot * 4);   // -> off after scan/fill
    const size_t zero_bytes = (size_t)(wsp - (char*)d_ws);
    int*   part   = (int*)alloc((size_t)(NB + 1) * 4);
    int*   adj    = (int*)alloc((size_t)4 * E * 4);
    float* aggT_c = (float*)alloc((size_t)Nc * 85 * 4);
    float* aggT_m = (float*)alloc((size_t)Nm * 85 * 4);
    float* wsum   = (float*)alloc((size_t)85 * 64 * 4);
    float* bsum   = (float*)alloc((size_t)64 * 4);
    float* z1     = (float*)alloc((size_t)Nc * 64 * 4);
    float* z2     = (float*)alloc((size_t)Nm * 64 * 4);
    (void)ws_size; (void)n_in; (void)out_size;

    hipMemsetAsync(d_ws, 0, zero_bytes, stream);   // zero cnt only

    const dim3 blk(256);
    const int gE = MIN((E + 255) / 256, 2048);
    auto tiles = [](int M) { return (M + 63) / 64; };

    // weight precompute
    prep<<<(85 * 64 + 255) / 256, blk, 0, stream>>>(w1_dst_t, b1_t, wsum, bsum);

    // ---- CSR build ----
    hist<<<gE, blk, 0, stream>>>(src_pays, dst_pays, src_recv, dst_recv, E, Nc, Nm, Nt, cnt);
    scan_p1<<<NB, blk, 0, stream>>>(cnt, Ntot, part);
    scan_p2<<<1, blk, 0, stream>>>(part, NB);
    scan_p3<<<NB, blk, 0, stream>>>(cnt, Ntot, part);
    fill<<<gE, blk, 0, stream>>>(src_pays, dst_pays, src_recv, dst_recv, E, Nc, Nm, Nt, cnt, adj);

    // ---- conv1 wide aggregation: wave per node ----
    gather85<<<(Nc + Nm + 3) / 4, blk, 0, stream>>>(
        x_trans, cnt, adj, Nc, Nm, aggT_c, aggT_m);

    // ---- small fused pipelines: aggT -> h -> z ----
    fused_small<<<tiles(Nc), blk, 0, stream>>>(
        aggT_c, Nc, w1_src_r, b1_r, x_card, w1_dst_r, w2_l, z1);
    fused_small<<<tiles(Nm), blk, 0, stream>>>(
        aggT_m, Nm, w1_src_r + 85 * 64, b1_r + 64, x_merch, w1_dst_r + 64,
        w2_l + 64 * 64, z2);

    // ---- megakernel: x_trans -> h_t -> v0,v1 (+scalar & z gathers) -> out ----
    mega_tf<<<tiles(Nt), blk, 0, stream>>>(
        x_trans, Nt, wsum, bsum,
        x_card, w1_src_t, x_merch, w1_src_t + 64,
        w2_r, b2, z1, z2,
        cnt, adj, Nc + Nm, Nc + Nm + Nt,
        w_lin, b_lin, out);
}

// Round 8
// 705.841 us; speedup vs baseline: 1.6252x; 1.0305x over previous
//
#include <hip/hip_runtime.h>
#include <hip/hip_bf16.h>

#ifndef MIN
#define MIN(a,b) ((a)<(b)?(a):(b))
#endif

#define RFL(x) __builtin_amdgcn_readfirstlane(x)

// ---------------------------------------------------------------------------
// gather_scalar: agg_c[t] = sum x_card[adjT0(t)], agg_m[t] = sum x_merch[adjT1(t)]
// Thread per transaction; high TLP hides the off->adj->x chain.
// ---------------------------------------------------------------------------
__global__ __launch_bounds__(256)
void gather_scalar(const float* __restrict__ x_card, const float* __restrict__ x_merch,
                   const int* __restrict__ off, const int* __restrict__ adj,
                   int Nc, int Nm, int Nt,
                   float* __restrict__ agg_c, float* __restrict__ agg_m)
{
    const int stride = gridDim.x * 256;
    const int b0 = Nc + Nm, b1 = Nc + Nm + Nt;
    for (int t = blockIdx.x * 256 + threadIdx.x; t < Nt; t += stride) {
        {
            const int i0 = b0 + t;
            float a = 0.f;
            for (int j = off[i0 - 1]; j < off[i0]; ++j) a += x_card[adj[j]];
            agg_c[t] = a;
        }
        {
            const int i1 = b1 + t;
            float a = 0.f;
            for (int j = off[i1 - 1]; j < off[i1]; ++j) a += x_merch[adj[j]];
            agg_m[t] = a;
        }
    }
}

// ---------------------------------------------------------------------------
// gather85: per card/merchant node, sum x_trans rows of its edge list.
// Wave per node; lane = channel; 4 independent row streams for MLP
// (merchant avg degree 50, card avg degree 10).
// ---------------------------------------------------------------------------
__global__ __launch_bounds__(256)
void gather85(const float* __restrict__ xt,
              const int* __restrict__ off, const int* __restrict__ adj,
              int Nc, int Nm,
              float* __restrict__ aggC, float* __restrict__ aggM)
{
    const int lane = threadIdx.x & 63;
    const int gw   = blockIdx.x * (blockDim.x >> 6) + (threadIdx.x >> 6);
    const int nw   = gridDim.x * (blockDim.x >> 6);
    const int N = Nc + Nm;
    for (int i = gw; i < N; i += nw) {
        const int s = (i == 0) ? 0 : off[i - 1];
        const int e = off[i];
        float a0 = 0.f, a1 = 0.f, b0 = 0.f, b1 = 0.f;
        float c0 = 0.f, c1 = 0.f, d0 = 0.f, d1 = 0.f;
        int j = s;
        for (; j + 3 < e; j += 4) {
            const float* x0 = xt + (size_t)adj[j]     * 85;
            const float* x1 = xt + (size_t)adj[j + 1] * 85;
            const float* x2 = xt + (size_t)adj[j + 2] * 85;
            const float* x3 = xt + (size_t)adj[j + 3] * 85;
            a0 += x0[lane]; b0 += x1[lane]; c0 += x2[lane]; d0 += x3[lane];
            if (lane < 21) {
                a1 += x0[64 + lane]; b1 += x1[64 + lane];
                c1 += x2[64 + lane]; d1 += x3[64 + lane];
            }
        }
        for (; j < e; ++j) {
            const float* xr = xt + (size_t)adj[j] * 85;
            a0 += xr[lane];
            if (lane < 21) a1 += xr[64 + lane];
        }
        a0 += b0; c0 += d0; a0 += c0;
        a1 += b1; c1 += d1; a1 += c1;
        float* dst = (i < Nc) ? aggC + (size_t)i * 85 : aggM + (size_t)(i - Nc) * 85;
        dst[lane] = a0;
        if (lane < 21) dst[64 + lane] = a1;
    }
}

// ---------------------------------------------------------------------------
// fused_small: per 64-row tile of `in` [M][85]:
//   h[r][c] = relu( in[r,:]@Wsum[:,c] + bsum[c] + s1[r]*wv1[c] )
//   out0[r][c] = h[r,:]@W2[:,c]
// h aliased into xbuf (pitch 85) -> 22KB LDS, 7 blocks/CU.
// ---------------------------------------------------------------------------
__global__ __launch_bounds__(256, 7)
void fused_small(const float* __restrict__ in, int M,
                 const float* __restrict__ Wsum,   // [85][64]
                 const float* __restrict__ bsum,   // [64]
                 const float* __restrict__ s1, const float* __restrict__ wv1,
                 const float* __restrict__ W2,     // [64][64]
                 float* __restrict__ out0)
{
    constexpr int K = 85;
    __shared__ float xbuf[64 * K];
    const int tid  = threadIdx.x;
    const int lane = tid & 63;
    const int wid  = tid >> 6;
    const int c0   = RFL(wid * 16);

    const int ntiles = (M + 63) >> 6;
    for (int t = blockIdx.x; t < ntiles; t += gridDim.x) {
        const int base = t << 6;
        const int rows = MIN(64, M - base);
        __syncthreads();
        {
            const int nw = rows * K;
            const float4* s4 = reinterpret_cast<const float4*>(in + (size_t)base * K);
            const int nv = nw >> 2;
            for (int i = tid; i < nv; i += 256)
                reinterpret_cast<float4*>(xbuf)[i] = s4[i];
            for (int i = (nv << 2) + tid; i < nw; i += 256)
                xbuf[i] = in[(size_t)base * K + i];
        }
        __syncthreads();
        // phase 1
        float acc[16];
#pragma unroll
        for (int j = 0; j < 16; ++j) acc[j] = bsum[c0 + j];
        {
            const float sv1 = (lane < rows) ? s1[base + lane] : 0.f;
#pragma unroll
            for (int j = 0; j < 16; ++j) acc[j] = fmaf(sv1, wv1[c0 + j], acc[j]);
        }
        {
            const float* xr = xbuf + lane * K;
#pragma unroll 5
            for (int k = 0; k < K; ++k) {
                const float xk = xr[k];
                const float* wk = Wsum + k * 64 + c0;
#pragma unroll
                for (int j = 0; j < 16; ++j) acc[j] = fmaf(xk, wk[j], acc[j]);
            }
        }
        __syncthreads();          // all phase-1 xbuf reads done
#pragma unroll
        for (int j = 0; j < 16; ++j) xbuf[lane * K + c0 + j] = fmaxf(acc[j], 0.f);
        __syncthreads();
        // phase 2
        float a2[16];
#pragma unroll
        for (int j = 0; j < 16; ++j) a2[j] = 0.f;
        {
            const float* hr = xbuf + lane * K;
#pragma unroll 4
            for (int k = 0; k < 64; ++k) {
                const float hk = hr[k];
                const float* wk = W2 + k * 64 + c0;
#pragma unroll
                for (int j = 0; j < 16; ++j) a2[j] = fmaf(hk, wk[j], a2[j]);
            }
        }
        if (lane < rows) {
            float* o0 = out0 + (size_t)(base + lane) * 64 + c0;
#pragma unroll
            for (int j4 = 0; j4 < 4; ++j4)
                reinterpret_cast<float4*>(o0)[j4] =
                    make_float4(a2[4*j4], a2[4*j4+1], a2[4*j4+2], a2[4*j4+3]);
        }
    }
}

// ---------------------------------------------------------------------------
// mega_tf: per 64-row tile of transactions:
//   h[r][c]  = relu( x[r,:]@Wsum[:,c] + bsum[c] + s1[r]*wv1[c] + s2[r]*wv2[c] )
//   vR[r][c] = h[r,:]@W2[R][:,c] + b2v[R][c] + sum_{e in adjR(r)} zR[e][c]
//   out[r][o] = bl[o] + sum_c relu(v0)*wl[c][o] + relu(v1)*wl[64+c][o]
// z-segment bounds + first adj prefetched at tile start (hidden under FMAs).
// ---------------------------------------------------------------------------
__global__ __launch_bounds__(256, 7)
void mega_tf(const float* __restrict__ in, int M,
             const float* __restrict__ Wsum,   // [85][64]
             const float* __restrict__ bsum,   // [64]
             const float* __restrict__ s1, const float* __restrict__ wv1,
             const float* __restrict__ s2, const float* __restrict__ wv2,
             const float* __restrict__ W2,     // [2][64][64] (w2_r)
             const float* __restrict__ b2v,    // [2][64]
             const float* __restrict__ z1, const float* __restrict__ z2,
             const int* __restrict__ off, const int* __restrict__ adj,
             int zb0, int zb1,                 // segment bases: Nc+Nm, Nc+Nm+Nt
             const float* __restrict__ wl, const float* __restrict__ bl,
             float* __restrict__ out)
{
    constexpr int K = 85;
    __shared__ float xbuf[64 * K];
    __shared__ float obuf[64][2];
    const int tid  = threadIdx.x;
    const int lane = tid & 63;
    const int wid  = tid >> 6;
    const int c0   = RFL(wid * 16);

    const int ntiles = (M + 63) >> 6;
    for (int t = blockIdx.x; t < ntiles; t += gridDim.x) {
        const int base = t << 6;
        const int rows = MIN(64, M - base);

        // ---- prefetch z-segment bounds + first adj (global, no barrier dep)
        int e00 = 0, e01 = 0, e10 = 0, e11 = 0, ja0 = 0, ja1 = 0;
        float sv1 = 0.f, sv2 = 0.f;
        if (lane < rows) {
            const int i0 = zb0 + base + lane;
            const int i1 = zb1 + base + lane;
            e00 = off[i0 - 1]; e01 = off[i0];
            e10 = off[i1 - 1]; e11 = off[i1];
            sv1 = s1[base + lane];
            sv2 = s2[base + lane];
        }
        if (e00 < e01) ja0 = adj[e00];
        if (e10 < e11) ja1 = adj[e10];

        __syncthreads();
        // ---- stage x tile ----
        {
            const int nw = rows * K;
            const float4* s4 = reinterpret_cast<const float4*>(in + (size_t)base * K);
            const int nv = nw >> 2;
            for (int i = tid; i < nv; i += 256)
                reinterpret_cast<float4*>(xbuf)[i] = s4[i];
            for (int i = (nv << 2) + tid; i < nw; i += 256)
                xbuf[i] = in[(size_t)base * K + i];
        }
        if (tid < 128) ((float*)obuf)[tid] = 0.f;
        __syncthreads();
        // ---- phase 1 ----
        float acc[16];
#pragma unroll
        for (int j = 0; j < 16; ++j) acc[j] = bsum[c0 + j];
#pragma unroll
        for (int j = 0; j < 16; ++j) acc[j] = fmaf(sv1, wv1[c0 + j], acc[j]);
#pragma unroll
        for (int j = 0; j < 16; ++j) acc[j] = fmaf(sv2, wv2[c0 + j], acc[j]);
        {
            const float* xr = xbuf + lane * K;
#pragma unroll 5
            for (int k = 0; k < K; ++k) {
                const float xk = xr[k];
                const float* wk = Wsum + k * 64 + c0;
#pragma unroll
                for (int j = 0; j < 16; ++j) acc[j] = fmaf(xk, wk[j], acc[j]);
            }
        }
        __syncthreads();          // all phase-1 xbuf reads done
#pragma unroll
        for (int j = 0; j < 16; ++j) xbuf[lane * K + c0 + j] = fmaxf(acc[j], 0.f);
        __syncthreads();
        // ---- phase 2: v0, v1 ----
        float a0[16], a1[16];
#pragma unroll
        for (int j = 0; j < 16; ++j) {
            a0[j] = b2v[c0 + j];
            a1[j] = b2v[64 + c0 + j];
        }
        {
            const float* hr = xbuf + lane * K;
#pragma unroll 4
            for (int k = 0; k < 64; ++k) {
                const float hk = hr[k];
                const float* wk0 = W2 + k * 64 + c0;
                const float* wk1 = W2 + 4096 + k * 64 + c0;
#pragma unroll
                for (int j = 0; j < 16; ++j) {
                    a0[j] = fmaf(hk, wk0[j], a0[j]);
                    a1[j] = fmaf(hk, wk1[j], a1[j]);
                }
            }
        }
        // ---- z gathers (first adj prefetched) ----
        if (e00 < e01) {
            int a = ja0;
            for (int j = e00; j < e01; ++j) {
                const float4* zr = reinterpret_cast<const float4*>(
                    z1 + (size_t)a * 64 + c0);
#pragma unroll
                for (int q = 0; q < 4; ++q) {
                    const float4 v = zr[q];
                    a0[4*q+0] += v.x; a0[4*q+1] += v.y;
                    a0[4*q+2] += v.z; a0[4*q+3] += v.w;
                }
                if (j + 1 < e01) a = adj[j + 1];
            }
        }
        if (e10 < e11) {
            int a = ja1;
            for (int j = e10; j < e11; ++j) {
                const float4* zr = reinterpret_cast<const float4*>(
                    z2 + (size_t)a * 64 + c0);
#pragma unroll
                for (int q = 0; q < 4; ++q) {
                    const float4 v = zr[q];
                    a1[4*q+0] += v.x; a1[4*q+1] += v.y;
                    a1[4*q+2] += v.z; a1[4*q+3] += v.w;
                }
                if (j + 1 < e11) a = adj[j + 1];
            }
        }
        // ---- relu + partial projection for this wave's 16 columns ----
        float pa = 0.f, pb = 0.f;
#pragma unroll
        for (int j = 0; j < 16; ++j) {
            const int c = c0 + j;
            const float v0 = fmaxf(a0[j], 0.f);
            const float v1 = fmaxf(a1[j], 0.f);
            pa += v0 * wl[c * 2 + 0] + v1 * wl[(64 + c) * 2 + 0];
            pb += v0 * wl[c * 2 + 1] + v1 * wl[(64 + c) * 2 + 1];
        }
        atomicAdd(&obuf[lane][0], pa);
        atomicAdd(&obuf[lane][1], pb);
        __syncthreads();
        if (tid < 2 * rows) {
            const int r = tid >> 1, o = tid & 1;
            out[(size_t)(base + r) * 2 + o] = obuf[r][o] + bl[o];
        }
    }
}

// ---------------------------------------------------------------------------
__global__ __launch_bounds__(256)
void prep(const float* __restrict__ w1dt, const float* __restrict__ b1t,
          float* __restrict__ wsum, float* __restrict__ bsum)
{
    const int i = blockIdx.x * 256 + threadIdx.x;
    if (i < 85 * 64) wsum[i] = w1dt[i] + w1dt[85 * 64 + i];
    if (i < 64)      bsum[i] = b1t[i] + b1t[64 + i];
}

// ---------------------------------------------------------------------------
// CSR build over ONE concatenated key space:
//   [0,Nc): card (pays src)              payload dst_pays
//   [Nc,Nc+Nm): merchant (recv src)      payload dst_recv
//   [Nc+Nm,+Nt): transaction (pays dst)  payload src_pays
//   [Nc+Nm+Nt,+Nt): transaction (recv)   payload src_recv
// ---------------------------------------------------------------------------
__global__ __launch_bounds__(256)
void hist(const int* __restrict__ sp, const int* __restrict__ dp,
          const int* __restrict__ sr, const int* __restrict__ dr,
          int E, int Nc, int Nm, int Nt, int* __restrict__ cnt)
{
    const int stride = gridDim.x * 256;
    for (int e = blockIdx.x * 256 + threadIdx.x; e < E; e += stride) {
        atomicAdd(&cnt[sp[e]], 1);
        atomicAdd(&cnt[Nc + sr[e]], 1);
        atomicAdd(&cnt[Nc + Nm + dp[e]], 1);
        atomicAdd(&cnt[Nc + Nm + Nt + dr[e]], 1);
    }
}

__global__ __launch_bounds__(256)
void scan_p1(const int* __restrict__ cnt, int n, int* __restrict__ part)
{
    __shared__ int sdata[256];
    const int b = blockIdx.x, t = threadIdx.x;
    const int base = b * 4096;
    int s = 0;
    for (int i = t; i < 4096; i += 256) {
        const int idx = base + i;
        s += (idx < n) ? cnt[idx] : 0;
    }
    sdata[t] = s; __syncthreads();
    for (int off = 128; off > 0; off >>= 1) {
        if (t < off) sdata[t] += sdata[t + off];
        __syncthreads();
    }
    if (t == 0) part[b] = sdata[0];
}

__global__ __launch_bounds__(256)
void scan_p2(int* __restrict__ part, int nb)
{
    __shared__ int sdata[256];
    const int t = threadIdx.x;
    int carry = 0;
    for (int base = 0; base < nb; base += 256) {
        const int idx = base + t;
        const int v = (idx < nb) ? part[idx] : 0;
        sdata[t] = v; __syncthreads();
        for (int off = 1; off < 256; off <<= 1) {
            const int x = (t >= off) ? sdata[t - off] : 0;
            __syncthreads();
            sdata[t] += x;
            __syncthreads();
        }
        const int incl  = sdata[t];
        const int total = sdata[255];
        if (idx < nb) part[idx] = carry + incl - v;
        carry += total;
        __syncthreads();
    }
}

__global__ __launch_bounds__(256)
void scan_p3(int* __restrict__ cnt, int n, const int* __restrict__ part)
{
    __shared__ int sums[256];
    const int b = blockIdx.x, t = threadIdx.x;
    const int base = b * 4096 + t * 16;
    int v[16];
    int s = 0;
#pragma unroll
    for (int j = 0; j < 16; ++j) {
        const int idx = base + j;
        v[j] = (idx < n) ? cnt[idx] : 0;
        s += v[j];
    }
    sums[t] = s; __syncthreads();
    for (int off = 1; off < 256; off <<= 1) {
        const int x = (t >= off) ? sums[t - off] : 0;
        __syncthreads();
        sums[t] += x;
        __syncthreads();
    }
    int run = part[b] + sums[t] - s;
#pragma unroll
    for (int j = 0; j < 16; ++j) {
        const int idx = base + j;
        if (idx < n) cnt[idx] = run;
        run += v[j];
    }
}

__global__ __launch_bounds__(256)
void fill(const int* __restrict__ sp, const int* __restrict__ dp,
          const int* __restrict__ sr, const int* __restrict__ dr,
          int E, int Nc, int Nm, int Nt,
          int* __restrict__ off, int* __restrict__ adj)
{
    const int stride = gridDim.x * 256;
    for (int e = blockIdx.x * 256 + threadIdx.x; e < E; e += stride) {
        int p;
        p = atomicAdd(&off[sp[e]], 1);                adj[p] = dp[e];
        p = atomicAdd(&off[Nc + sr[e]], 1);           adj[p] = dr[e];
        p = atomicAdd(&off[Nc + Nm + dp[e]], 1);      adj[p] = sp[e];
        p = atomicAdd(&off[Nc + Nm + Nt + dr[e]], 1); adj[p] = sr[e];
    }
}

// ---------------------------------------------------------------------------
extern "C" void kernel_launch(void* const* d_in, const int* in_sizes, int n_in,
                              void* d_out, int out_size, void* d_ws, size_t ws_size,
                              hipStream_t stream)
{
    const float* x_card   = (const float*)d_in[0];
    const float* x_merch  = (const float*)d_in[1];
    const float* x_trans  = (const float*)d_in[2];
    const float* w1_src_t = (const float*)d_in[3];   // [2,1,64]
    const float* w1_dst_t = (const float*)d_in[4];   // [2,85,64]
    const float* b1_t     = (const float*)d_in[5];   // [2,64]
    const float* w1_src_r = (const float*)d_in[6];   // [2,85,64]
    const float* w1_dst_r = (const float*)d_in[7];   // [2,1,64]
    const float* b1_r     = (const float*)d_in[8];   // [2,64]
    const float* w2_l     = (const float*)d_in[9];   // [4,64,64]
    const float* w2_r     = (const float*)d_in[10];  // [4,64,64]
    const float* b2       = (const float*)d_in[11];  // [4,64]
    const float* w_lin    = (const float*)d_in[12];  // [128,2]
    const float* b_lin    = (const float*)d_in[13];  // [2]
    const int*   src_pays = (const int*)d_in[14];
    const int*   dst_pays = (const int*)d_in[15];
    const int*   src_recv = (const int*)d_in[16];
    const int*   dst_recv = (const int*)d_in[17];
    float*       out      = (float*)d_out;

    const int Nc = in_sizes[0];
    const int Nm = in_sizes[1];
    const int Nt = in_sizes[2] / 85;
    const int E  = in_sizes[14];
    const int Ntot = Nc + Nm + 2 * Nt;
    const int NB   = (Ntot + 4095) / 4096;

    // workspace layout
    char* wsp = (char*)d_ws;
    auto alloc = [&](size_t bytes) -> void* {
        char* p = wsp;
        wsp += (bytes + 255) & ~(size_t)255;
        return (void*)p;
    };
    int*   cnt    = (int*)alloc((size_t)Ntot * 4);   // -> off after scan/fill
    const size_t zero_bytes = (size_t)(wsp - (char*)d_ws);
    int*   part   = (int*)alloc((size_t)(NB + 1) * 4);
    int*   adj    = (int*)alloc((size_t)4 * E * 4);
    float* agg_c  = (float*)alloc((size_t)Nt * 4);
    float* agg_m  = (float*)alloc((size_t)Nt * 4);
    float* aggT_c = (float*)alloc((size_t)Nc * 85 * 4);
    float* aggT_m = (float*)alloc((size_t)Nm * 85 * 4);
    float* wsum   = (float*)alloc((size_t)85 * 64 * 4);
    float* bsum   = (float*)alloc((size_t)64 * 4);
    float* z1     = (float*)alloc((size_t)Nc * 64 * 4);
    float* z2     = (float*)alloc((size_t)Nm * 64 * 4);
    (void)ws_size; (void)n_in; (void)out_size;

    hipMemsetAsync(d_ws, 0, zero_bytes, stream);   // zero cnt only

    const dim3 blk(256);
    const int gE = MIN((E + 255) / 256, 2048);
    auto tiles = [](int M) { return (M + 63) / 64; };

    // weight precompute
    prep<<<(85 * 64 + 255) / 256, blk, 0, stream>>>(w1_dst_t, b1_t, wsum, bsum);

    // ---- CSR build ----
    hist<<<gE, blk, 0, stream>>>(src_pays, dst_pays, src_recv, dst_recv, E, Nc, Nm, Nt, cnt);
    scan_p1<<<NB, blk, 0, stream>>>(cnt, Ntot, part);
    scan_p2<<<1, blk, 0, stream>>>(part, NB);
    scan_p3<<<NB, blk, 0, stream>>>(cnt, Ntot, part);
    fill<<<gE, blk, 0, stream>>>(src_pays, dst_pays, src_recv, dst_recv, E, Nc, Nm, Nt, cnt, adj);

    // ---- conv1 aggregations (pure gathers, high TLP) ----
    gather_scalar<<<MIN((Nt + 255) / 256, 2048), blk, 0, stream>>>(
        x_card, x_merch, cnt, adj, Nc, Nm, Nt, agg_c, agg_m);
    gather85<<<(Nc + Nm + 3) / 4, blk, 0, stream>>>(
        x_trans, cnt, adj, Nc, Nm, aggT_c, aggT_m);

    // ---- small fused pipelines: aggT -> h -> z ----
    fused_small<<<tiles(Nc), blk, 0, stream>>>(
        aggT_c, Nc, w1_src_r, b1_r, x_card, w1_dst_r, w2_l, z1);
    fused_small<<<tiles(Nm), blk, 0, stream>>>(
        aggT_m, Nm, w1_src_r + 85 * 64, b1_r + 64, x_merch, w1_dst_r + 64,
        w2_l + 64 * 64, z2);

    // ---- megakernel: x_trans -> h_t -> v0,v1 (+z gather) -> out ----
    mega_tf<<<tiles(Nt), blk, 0, stream>>>(
        x_trans, Nt, wsum, bsum,
        agg_c, w1_src_t, agg_m, w1_src_t + 64,
        w2_r, b2, z1, z2,
        cnt, adj, Nc + Nm, Nc + Nm + Nt,
        w_lin, b_lin, out);
}

// Round 9
// 617.062 us; speedup vs baseline: 1.8590x; 1.1439x over previous
//
#include <hip/hip_runtime.h>
#include <hip/hip_bf16.h>

#ifndef MIN
#define MIN(a,b) ((a)<(b)?(a):(b))
#endif

#define RFL(x) __builtin_amdgcn_readfirstlane(x)

// ---------------------------------------------------------------------------
// gather85: per card/merchant node, sum x_trans rows of its edge list.
// Wave per node; lane = channel; 4 independent row streams for MLP.
// ---------------------------------------------------------------------------
__global__ __launch_bounds__(256)
void gather85(const float* __restrict__ xt,
              const int* __restrict__ off, const int* __restrict__ adj,
              int Nc, int Nm,
              float* __restrict__ aggC, float* __restrict__ aggM)
{
    const int lane = threadIdx.x & 63;
    const int gw   = blockIdx.x * (blockDim.x >> 6) + (threadIdx.x >> 6);
    const int nw   = gridDim.x * (blockDim.x >> 6);
    const int N = Nc + Nm;
    for (int i = gw; i < N; i += nw) {
        const int s = (i == 0) ? 0 : off[i - 1];
        const int e = off[i];
        float a0 = 0.f, a1 = 0.f, b0 = 0.f, b1 = 0.f;
        float c0 = 0.f, c1 = 0.f, d0 = 0.f, d1 = 0.f;
        int j = s;
        for (; j + 3 < e; j += 4) {
            const float* x0 = xt + (size_t)adj[j]     * 85;
            const float* x1 = xt + (size_t)adj[j + 1] * 85;
            const float* x2 = xt + (size_t)adj[j + 2] * 85;
            const float* x3 = xt + (size_t)adj[j + 3] * 85;
            a0 += x0[lane]; b0 += x1[lane]; c0 += x2[lane]; d0 += x3[lane];
            if (lane < 21) {
                a1 += x0[64 + lane]; b1 += x1[64 + lane];
                c1 += x2[64 + lane]; d1 += x3[64 + lane];
            }
        }
        for (; j < e; ++j) {
            const float* xr = xt + (size_t)adj[j] * 85;
            a0 += xr[lane];
            if (lane < 21) a1 += xr[64 + lane];
        }
        a0 += b0; c0 += d0; a0 += c0;
        a1 += b1; c1 += d1; a1 += c1;
        float* dst = (i < Nc) ? aggC + (size_t)i * 85 : aggM + (size_t)(i - Nc) * 85;
        dst[lane] = a0;
        if (lane < 21) dst[64 + lane] = a1;
    }
}

// ---------------------------------------------------------------------------
// fused_small: per 64-row tile of `in` [M][85]:
//   h[r][c] = relu( in[r,:]@Wsum[:,c] + bsum[c] + s1[r]*wv1[c] )
//   out0[r][c] = h[r,:]@W2[:,c]
// h aliased into xbuf (pitch 85) -> 22KB LDS, 7 blocks/CU.
// ---------------------------------------------------------------------------
__global__ __launch_bounds__(256, 7)
void fused_small(const float* __restrict__ in, int M,
                 const float* __restrict__ Wsum,   // [85][64]
                 const float* __restrict__ bsum,   // [64]
                 const float* __restrict__ s1, const float* __restrict__ wv1,
                 const float* __restrict__ W2,     // [64][64]
                 float* __restrict__ out0)
{
    constexpr int K = 85;
    __shared__ float xbuf[64 * K];
    const int tid  = threadIdx.x;
    const int lane = tid & 63;
    const int wid  = tid >> 6;
    const int c0   = RFL(wid * 16);

    const int ntiles = (M + 63) >> 6;
    for (int t = blockIdx.x; t < ntiles; t += gridDim.x) {
        const int base = t << 6;
        const int rows = MIN(64, M - base);
        __syncthreads();
        {
            const int nw = rows * K;
            const float4* s4 = reinterpret_cast<const float4*>(in + (size_t)base * K);
            const int nv = nw >> 2;
            for (int i = tid; i < nv; i += 256)
                reinterpret_cast<float4*>(xbuf)[i] = s4[i];
            for (int i = (nv << 2) + tid; i < nw; i += 256)
                xbuf[i] = in[(size_t)base * K + i];
        }
        __syncthreads();
        // phase 1
        float acc[16];
#pragma unroll
        for (int j = 0; j < 16; ++j) acc[j] = bsum[c0 + j];
        {
            const float sv1 = (lane < rows) ? s1[base + lane] : 0.f;
#pragma unroll
            for (int j = 0; j < 16; ++j) acc[j] = fmaf(sv1, wv1[c0 + j], acc[j]);
        }
        {
            const float* xr = xbuf + lane * K;
#pragma unroll 5
            for (int k = 0; k < K; ++k) {
                const float xk = xr[k];
                const float* wk = Wsum + k * 64 + c0;
#pragma unroll
                for (int j = 0; j < 16; ++j) acc[j] = fmaf(xk, wk[j], acc[j]);
            }
        }
        __syncthreads();          // all phase-1 xbuf reads done
#pragma unroll
        for (int j = 0; j < 16; ++j) xbuf[lane * K + c0 + j] = fmaxf(acc[j], 0.f);
        __syncthreads();
        // phase 2
        float a2[16];
#pragma unroll
        for (int j = 0; j < 16; ++j) a2[j] = 0.f;
        {
            const float* hr = xbuf + lane * K;
#pragma unroll 4
            for (int k = 0; k < 64; ++k) {
                const float hk = hr[k];
                const float* wk = W2 + k * 64 + c0;
#pragma unroll
                for (int j = 0; j < 16; ++j) a2[j] = fmaf(hk, wk[j], a2[j]);
            }
        }
        if (lane < rows) {
            float* o0 = out0 + (size_t)(base + lane) * 64 + c0;
#pragma unroll
            for (int j4 = 0; j4 < 4; ++j4)
                reinterpret_cast<float4*>(o0)[j4] =
                    make_float4(a2[4*j4], a2[4*j4+1], a2[4*j4+2], a2[4*j4+3]);
        }
    }
}

// ---------------------------------------------------------------------------
// mega_tf (R5-proven form): per 64-row tile of transactions:
//   h[r][c]  = relu( x[r,:]@Wsum[:,c] + bsum[c] + s1[r]*wv1[c] + s2[r]*wv2[c] )
//   vR[r][c] = h[r,:]@W2[R][:,c] + b2v[R][c] + sum_{e in adjR(r)} zR[e][c]
//   out[r][o] = bl[o] + sum_c relu(v0)*wl[c][o] + relu(v1)*wl[64+c][o]
// No prefetch: z-segment offsets read inline AFTER phase 2 (vmcnt stays clean
// for the staging pipeline — R7/R8 prefetch variant measured 283 vs this 217).
// ---------------------------------------------------------------------------
__global__ __launch_bounds__(256, 6)
void mega_tf(const float* __restrict__ in, int M,
             const float* __restrict__ Wsum,   // [85][64]
             const float* __restrict__ bsum,   // [64]
             const float* __restrict__ s1, const float* __restrict__ wv1,
             const float* __restrict__ s2, const float* __restrict__ wv2,
             const float* __restrict__ W2,     // [2][64][64] (w2_r)
             const float* __restrict__ b2v,    // [2][64]
             const float* __restrict__ z1, const float* __restrict__ z2,
             const int* __restrict__ off, const int* __restrict__ adj,
             int zb0, int zb1,                 // segment bases: Nc+Nm, Nc+Nm+Nt
             const float* __restrict__ wl, const float* __restrict__ bl,
             float* __restrict__ out)
{
    constexpr int K = 85;
    __shared__ float xbuf[64 * K];
    __shared__ float obuf[64][2];
    const int tid  = threadIdx.x;
    const int lane = tid & 63;
    const int wid  = tid >> 6;
    const int c0   = RFL(wid * 16);

    const int ntiles = (M + 63) >> 6;
    for (int t = blockIdx.x; t < ntiles; t += gridDim.x) {
        const int base = t << 6;
        const int rows = MIN(64, M - base);
        __syncthreads();
        // ---- stage x tile ----
        {
            const int nw = rows * K;
            const float4* s4 = reinterpret_cast<const float4*>(in + (size_t)base * K);
            const int nv = nw >> 2;
            for (int i = tid; i < nv; i += 256)
                reinterpret_cast<float4*>(xbuf)[i] = s4[i];
            for (int i = (nv << 2) + tid; i < nw; i += 256)
                xbuf[i] = in[(size_t)base * K + i];
        }
        if (tid < 128) ((float*)obuf)[tid] = 0.f;
        __syncthreads();
        // ---- phase 1 ----
        float acc[16];
#pragma unroll
        for (int j = 0; j < 16; ++j) acc[j] = bsum[c0 + j];
        {
            const float sv1 = (lane < rows) ? s1[base + lane] : 0.f;
#pragma unroll
            for (int j = 0; j < 16; ++j) acc[j] = fmaf(sv1, wv1[c0 + j], acc[j]);
        }
        {
            const float sv2 = (lane < rows) ? s2[base + lane] : 0.f;
#pragma unroll
            for (int j = 0; j < 16; ++j) acc[j] = fmaf(sv2, wv2[c0 + j], acc[j]);
        }
        {
            const float* xr = xbuf + lane * K;
#pragma unroll 5
            for (int k = 0; k < K; ++k) {
                const float xk = xr[k];
                const float* wk = Wsum + k * 64 + c0;
#pragma unroll
                for (int j = 0; j < 16; ++j) acc[j] = fmaf(xk, wk[j], acc[j]);
            }
        }
        __syncthreads();          // all phase-1 xbuf reads done
#pragma unroll
        for (int j = 0; j < 16; ++j) xbuf[lane * K + c0 + j] = fmaxf(acc[j], 0.f);
        __syncthreads();
        // ---- phase 2: v0, v1 ----
        float a0[16], a1[16];
#pragma unroll
        for (int j = 0; j < 16; ++j) {
            a0[j] = b2v[c0 + j];
            a1[j] = b2v[64 + c0 + j];
        }
        {
            const float* hr = xbuf + lane * K;
#pragma unroll 4
            for (int k = 0; k < 64; ++k) {
                const float hk = hr[k];
                const float* wk0 = W2 + k * 64 + c0;
                const float* wk1 = W2 + 4096 + k * 64 + c0;
#pragma unroll
                for (int j = 0; j < 16; ++j) {
                    a0[j] = fmaf(hk, wk0[j], a0[j]);
                    a1[j] = fmaf(hk, wk1[j], a1[j]);
                }
            }
        }
        // ---- z gathers (per-lane edge lists, avg degree ~1) ----
        if (lane < rows) {
            {
                const int i0 = zb0 + base + lane;
                const int e0 = off[i0 - 1], e1 = off[i0];
                for (int j = e0; j < e1; ++j) {
                    const float4* zr = reinterpret_cast<const float4*>(
                        z1 + (size_t)adj[j] * 64 + c0);
#pragma unroll
                    for (int q = 0; q < 4; ++q) {
                        const float4 v = zr[q];
                        a0[4*q+0] += v.x; a0[4*q+1] += v.y;
                        a0[4*q+2] += v.z; a0[4*q+3] += v.w;
                    }
                }
            }
            {
                const int i1 = zb1 + base + lane;
                const int e0 = off[i1 - 1], e1 = off[i1];
                for (int j = e0; j < e1; ++j) {
                    const float4* zr = reinterpret_cast<const float4*>(
                        z2 + (size_t)adj[j] * 64 + c0);
#pragma unroll
                    for (int q = 0; q < 4; ++q) {
                        const float4 v = zr[q];
                        a1[4*q+0] += v.x; a1[4*q+1] += v.y;
                        a1[4*q+2] += v.z; a1[4*q+3] += v.w;
                    }
                }
            }
        }
        // ---- relu + partial projection for this wave's 16 columns ----
        float pa = 0.f, pb = 0.f;
#pragma unroll
        for (int j = 0; j < 16; ++j) {
            const int c = c0 + j;
            const float v0 = fmaxf(a0[j], 0.f);
            const float v1 = fmaxf(a1[j], 0.f);
            pa += v0 * wl[c * 2 + 0] + v1 * wl[(64 + c) * 2 + 0];
            pb += v0 * wl[c * 2 + 1] + v1 * wl[(64 + c) * 2 + 1];
        }
        atomicAdd(&obuf[lane][0], pa);
        atomicAdd(&obuf[lane][1], pb);
        __syncthreads();
        if (tid < 2 * rows) {
            const int r = tid >> 1, o = tid & 1;
            out[(size_t)(base + r) * 2 + o] = obuf[r][o] + bl[o];
        }
    }
}

// ---------------------------------------------------------------------------
__global__ __launch_bounds__(256)
void prep(const float* __restrict__ w1dt, const float* __restrict__ b1t,
          float* __restrict__ wsum, float* __restrict__ bsum)
{
    const int i = blockIdx.x * 256 + threadIdx.x;
    if (i < 85 * 64) wsum[i] = w1dt[i] + w1dt[85 * 64 + i];
    if (i < 64)      bsum[i] = b1t[i] + b1t[64 + i];
}

// ---------------------------------------------------------------------------
// CSR build over ONE concatenated key space:
//   [0,Nc): card (pays src)              payload dst_pays
//   [Nc,Nc+Nm): merchant (recv src)      payload dst_recv
//   [Nc+Nm,+Nt): transaction (pays dst)  payload src_pays
//   [Nc+Nm+Nt,+Nt): transaction (recv)   payload src_recv
// ---------------------------------------------------------------------------
__global__ __launch_bounds__(256)
void hist(const int* __restrict__ sp, const int* __restrict__ dp,
          const int* __restrict__ sr, const int* __restrict__ dr,
          int E, int Nc, int Nm, int Nt, int* __restrict__ cnt)
{
    const int stride = gridDim.x * 256;
    for (int e = blockIdx.x * 256 + threadIdx.x; e < E; e += stride) {
        atomicAdd(&cnt[sp[e]], 1);
        atomicAdd(&cnt[Nc + sr[e]], 1);
        atomicAdd(&cnt[Nc + Nm + dp[e]], 1);
        atomicAdd(&cnt[Nc + Nm + Nt + dr[e]], 1);
    }
}

__global__ __launch_bounds__(256)
void scan_p1(const int* __restrict__ cnt, int n, int* __restrict__ part)
{
    __shared__ int sdata[256];
    const int b = blockIdx.x, t = threadIdx.x;
    const int base = b * 4096;
    int s = 0;
    for (int i = t; i < 4096; i += 256) {
        const int idx = base + i;
        s += (idx < n) ? cnt[idx] : 0;
    }
    sdata[t] = s; __syncthreads();
    for (int off = 128; off > 0; off >>= 1) {
        if (t < off) sdata[t] += sdata[t + off];
        __syncthreads();
    }
    if (t == 0) part[b] = sdata[0];
}

__global__ __launch_bounds__(256)
void scan_p2(int* __restrict__ part, int nb)
{
    __shared__ int sdata[256];
    const int t = threadIdx.x;
    int carry = 0;
    for (int base = 0; base < nb; base += 256) {
        const int idx = base + t;
        const int v = (idx < nb) ? part[idx] : 0;
        sdata[t] = v; __syncthreads();
        for (int off = 1; off < 256; off <<= 1) {
            const int x = (t >= off) ? sdata[t - off] : 0;
            __syncthreads();
            sdata[t] += x;
            __syncthreads();
        }
        const int incl  = sdata[t];
        const int total = sdata[255];
        if (idx < nb) part[idx] = carry + incl - v;
        carry += total;
        __syncthreads();
    }
}

__global__ __launch_bounds__(256)
void scan_p3(int* __restrict__ cnt, int n, const int* __restrict__ part)
{
    __shared__ int sums[256];
    const int b = blockIdx.x, t = threadIdx.x;
    const int base = b * 4096 + t * 16;
    int v[16];
    int s = 0;
#pragma unroll
    for (int j = 0; j < 16; ++j) {
        const int idx = base + j;
        v[j] = (idx < n) ? cnt[idx] : 0;
        s += v[j];
    }
    sums[t] = s; __syncthreads();
    for (int off = 1; off < 256; off <<= 1) {
        const int x = (t >= off) ? sums[t - off] : 0;
        __syncthreads();
        sums[t] += x;
        __syncthreads();
    }
    int run = part[b] + sums[t] - s;
#pragma unroll
    for (int j = 0; j < 16; ++j) {
        const int idx = base + j;
        if (idx < n) cnt[idx] = run;
        run += v[j];
    }
}

// ---------------------------------------------------------------------------
// fill: CSR adjacency fill + scalar conv1 aggregates fused (2 f32 atomics/edge
// on L2-resident 2/4 MB buffers — cheap, replaces a whole gather kernel).
//   agg_c[dp[e]] += x_card[sp[e]];  agg_m[dr[e]] += x_merch[sr[e]]
// ---------------------------------------------------------------------------
__global__ __launch_bounds__(256)
void fill(const int* __restrict__ sp, const int* __restrict__ dp,
          const int* __restrict__ sr, const int* __restrict__ dr,
          int E, int Nc, int Nm, int Nt,
          int* __restrict__ off, int* __restrict__ adj,
          const float* __restrict__ x_card, const float* __restrict__ x_merch,
          float* __restrict__ agg_c, float* __restrict__ agg_m)
{
    const int stride = gridDim.x * 256;
    for (int e = blockIdx.x * 256 + threadIdx.x; e < E; e += stride) {
        const int vsp = sp[e], vdp = dp[e], vsr = sr[e], vdr = dr[e];
        int p;
        p = atomicAdd(&off[vsp], 1);                adj[p] = vdp;
        p = atomicAdd(&off[Nc + vsr], 1);           adj[p] = vdr;
        p = atomicAdd(&off[Nc + Nm + vdp], 1);      adj[p] = vsp;
        p = atomicAdd(&off[Nc + Nm + Nt + vdr], 1); adj[p] = vsr;
        atomicAdd(&agg_c[vdp], x_card[vsp]);
        atomicAdd(&agg_m[vdr], x_merch[vsr]);
    }
}

// ---------------------------------------------------------------------------
extern "C" void kernel_launch(void* const* d_in, const int* in_sizes, int n_in,
                              void* d_out, int out_size, void* d_ws, size_t ws_size,
                              hipStream_t stream)
{
    const float* x_card   = (const float*)d_in[0];
    const float* x_merch  = (const float*)d_in[1];
    const float* x_trans  = (const float*)d_in[2];
    const float* w1_src_t = (const float*)d_in[3];   // [2,1,64]
    const float* w1_dst_t = (const float*)d_in[4];   // [2,85,64]
    const float* b1_t     = (const float*)d_in[5];   // [2,64]
    const float* w1_src_r = (const float*)d_in[6];   // [2,85,64]
    const float* w1_dst_r = (const float*)d_in[7];   // [2,1,64]
    const float* b1_r     = (const float*)d_in[8];   // [2,64]
    const float* w2_l     = (const float*)d_in[9];   // [4,64,64]
    const float* w2_r     = (const float*)d_in[10];  // [4,64,64]
    const float* b2       = (const float*)d_in[11];  // [4,64]
    const float* w_lin    = (const float*)d_in[12];  // [128,2]
    const float* b_lin    = (const float*)d_in[13];  // [2]
    const int*   src_pays = (const int*)d_in[14];
    const int*   dst_pays = (const int*)d_in[15];
    const int*   src_recv = (const int*)d_in[16];
    const int*   dst_recv = (const int*)d_in[17];
    float*       out      = (float*)d_out;

    const int Nc = in_sizes[0];
    const int Nm = in_sizes[1];
    const int Nt = in_sizes[2] / 85;
    const int E  = in_sizes[14];
    const int Ntot = Nc + Nm + 2 * Nt;
    const int NB   = (Ntot + 4095) / 4096;

    // workspace layout
    char* wsp = (char*)d_ws;
    auto alloc = [&](size_t bytes) -> void* {
        char* p = wsp;
        wsp += (bytes + 255) & ~(size_t)255;
        return (void*)p;
    };
    int*   cnt    = (int*)alloc((size_t)Ntot * 4);   // -> off after scan/fill
    float* agg_c  = (float*)alloc((size_t)Nt * 4);
    float* agg_m  = (float*)alloc((size_t)Nt * 4);
    const size_t zero_bytes = (size_t)(wsp - (char*)d_ws);
    int*   part   = (int*)alloc((size_t)(NB + 1) * 4);
    int*   adj    = (int*)alloc((size_t)4 * E * 4);
    float* aggT_c = (float*)alloc((size_t)Nc * 85 * 4);
    float* aggT_m = (float*)alloc((size_t)Nm * 85 * 4);
    float* wsum   = (float*)alloc((size_t)85 * 64 * 4);
    float* bsum   = (float*)alloc((size_t)64 * 4);
    float* z1     = (float*)alloc((size_t)Nc * 64 * 4);
    float* z2     = (float*)alloc((size_t)Nm * 64 * 4);
    (void)ws_size; (void)n_in; (void)out_size;

    hipMemsetAsync(d_ws, 0, zero_bytes, stream);   // zero cnt + agg_c/agg_m

    const dim3 blk(256);
    const int gE = MIN((E + 255) / 256, 2048);
    auto tiles = [](int M) { return (M + 63) / 64; };

    // weight precompute
    prep<<<(85 * 64 + 255) / 256, blk, 0, stream>>>(w1_dst_t, b1_t, wsum, bsum);

    // ---- CSR build (+fused scalar aggregates in fill) ----
    hist<<<gE, blk, 0, stream>>>(src_pays, dst_pays, src_recv, dst_recv, E, Nc, Nm, Nt, cnt);
    scan_p1<<<NB, blk, 0, stream>>>(cnt, Ntot, part);
    scan_p2<<<1, blk, 0, stream>>>(part, NB);
    scan_p3<<<NB, blk, 0, stream>>>(cnt, Ntot, part);
    fill<<<gE, blk, 0, stream>>>(src_pays, dst_pays, src_recv, dst_recv, E, Nc, Nm, Nt,
                                 cnt, adj, x_card, x_merch, agg_c, agg_m);

    // ---- conv1 wide aggregation: wave per node ----
    gather85<<<(Nc + Nm + 3) / 4, blk, 0, stream>>>(
        x_trans, cnt, adj, Nc, Nm, aggT_c, aggT_m);

    // ---- small fused pipelines: aggT -> h -> z ----
    fused_small<<<tiles(Nc), blk, 0, stream>>>(
        aggT_c, Nc, w1_src_r, b1_r, x_card, w1_dst_r, w2_l, z1);
    fused_small<<<tiles(Nm), blk, 0, stream>>>(
        aggT_m, Nm, w1_src_r + 85 * 64, b1_r + 64, x_merch, w1_dst_r + 64,
        w2_l + 64 * 64, z2);

    // ---- megakernel: x_trans -> h_t -> v0,v1 (+z gather) -> out ----
    mega_tf<<<tiles(Nt), blk, 0, stream>>>(
        x_trans, Nt, wsum, bsum,
        agg_c, w1_src_t, agg_m, w1_src_t + 64,
        w2_r, b2, z1, z2,
        cnt, adj, Nc + Nm, Nc + Nm + Nt,
        w_lin, b_lin, out);
}